// Round 6
// baseline (604.170 us; speedup 1.0000x reference)
//
#include <hip/hip_runtime.h>
#include <math.h>

#define N_NODES   50000
#define N_EDGES   1600000
#define N_HEADS   8
#define IN_DIM    512
#define OUT_DIM   64
#define FEAT_DIM  512            // N_HEADS * OUT_DIM
#define LRELU_A   0.2f
#define M_TILES   391            // ceil(50000/128)
#define M_PAD     (M_TILES*128)  // 50048 rows in xh (tail rows read but never stored)

// dst-banding keys: adjacency stored grouped by (src, dst>>11). Read FLAT per
// node it is a dst-block-sorted edge list -> monotone sweep of dst space.
#define DBLK_SHIFT 11
#define NBLK       25                       // ceil(50000/2048)
#define NKEYS      (N_NODES * NBLK)         // 1,250,000
#define KSCAN_BLK  ((NKEYS + 1023) / 1024)  // 1221

// fused-launch geometry
#define EDGE_BLK   782                      // ceil(1.6M / (256*8))
#define CVT_BLK    25000                    // 25.6M bf16 / 4-per-thread / 256
#define GEMM_TILES 1564                     // 391 * 4

typedef __attribute__((ext_vector_type(8))) short bf16x8;
typedef __attribute__((ext_vector_type(4))) short bf16x4;
typedef __attribute__((ext_vector_type(4))) float f32x4;

__device__ inline unsigned short f2bf(float f) {
    unsigned int u = __float_as_uint(f);
    u = (u + 0x7FFFu + ((u >> 16) & 1u)) >> 16;   // round-to-nearest-even
    return (unsigned short)u;
}
__device__ inline float bf2f(short s) {
    return __uint_as_float(((unsigned int)(unsigned short)s) << 16);
}

// ---------------------------------------------------------------------------
// Fused: x (fp32 [N][512]) -> xh (bf16)   ||   banded-key histogram (count).
// ---------------------------------------------------------------------------
__global__ __launch_bounds__(256) void convert_count(const float* __restrict__ x,
                                                     unsigned short* __restrict__ xh,
                                                     const int* __restrict__ src,
                                                     const int* __restrict__ dst,
                                                     int* __restrict__ cnt) {
    const int id = blockIdx.x;
    if (id < 2 * EDGE_BLK && (id & 1)) {
        // ---- count role (unroll 8) ----
        const int blk = id >> 1;
        const int e = (blk * 256 + threadIdx.x) * 8;
        if (e < N_EDGES) {
            int4 s0 = *(const int4*)&src[e];
            int4 s1 = *(const int4*)&src[e + 4];
            int4 d0 = *(const int4*)&dst[e];
            int4 d1 = *(const int4*)&dst[e + 4];
            atomicAdd(&cnt[s0.x * NBLK + (d0.x >> DBLK_SHIFT)], 1);
            atomicAdd(&cnt[s0.y * NBLK + (d0.y >> DBLK_SHIFT)], 1);
            atomicAdd(&cnt[s0.z * NBLK + (d0.z >> DBLK_SHIFT)], 1);
            atomicAdd(&cnt[s0.w * NBLK + (d0.w >> DBLK_SHIFT)], 1);
            atomicAdd(&cnt[s1.x * NBLK + (d1.x >> DBLK_SHIFT)], 1);
            atomicAdd(&cnt[s1.y * NBLK + (d1.y >> DBLK_SHIFT)], 1);
            atomicAdd(&cnt[s1.z * NBLK + (d1.z >> DBLK_SHIFT)], 1);
            atomicAdd(&cnt[s1.w * NBLK + (d1.w >> DBLK_SHIFT)], 1);
        }
        return;
    }
    // ---- convert role ----
    const int c = (id < 2 * EDGE_BLK) ? (id >> 1) : (id - EDGE_BLK);
    const int i = c * 256 + threadIdx.x;   // float4 index
    if (i >= N_NODES * IN_DIM / 4) return;
    float4 v = ((const float4*)x)[i];
    ushort4 o;
    o.x = f2bf(v.x); o.y = f2bf(v.y); o.z = f2bf(v.z); o.w = f2bf(v.w);
    ((ushort4*)xh)[i] = o;
}

// ---------------------------------------------------------------------------
// W (fp32 [8][512][64]) -> Bt (bf16 [n=512][k=512]), Bt[n][k] = W[n>>6][k][n&63]
// ---------------------------------------------------------------------------
__global__ __launch_bounds__(256) void prep_b(const float* __restrict__ W,
                                              unsigned short* __restrict__ Bt) {
    int t = blockIdx.x * blockDim.x + threadIdx.x;   // t = n*512 + k
    if (t >= FEAT_DIM * IN_DIM) return;
    int n = t >> 9, k = t & 511;
    int h = n >> 6, o = n & 63;
    Bt[t] = f2bf(W[(size_t)h * IN_DIM * OUT_DIM + (size_t)k * OUT_DIM + o]);
}

// ---------------------------------------------------------------------------
// Fused: MFMA GEMM (feat = xh @ Bt^T)  ||  banded scatter (CSR fill).
// ---------------------------------------------------------------------------
__global__ __launch_bounds__(256) void gemm_scatter(const unsigned short* __restrict__ xh,
                                                    const unsigned short* __restrict__ Bt,
                                                    unsigned short* __restrict__ feat_h,
                                                    const int* __restrict__ src,
                                                    const int* __restrict__ dst,
                                                    int* __restrict__ cursor,
                                                    int* __restrict__ csr_dst) {
    __shared__ __align__(16) unsigned short As[128 * 32];  // [m][k], 64 B rows
    __shared__ __align__(16) unsigned short Bs[128 * 32];  // [n][k]
    const unsigned id = blockIdx.x;
    const unsigned q3 = id / 3u;
    const unsigned r3 = id - q3 * 3u;

    if (r3 == 2u) {
        // ---- scatter role (unroll 8) ----
        const int e = ((int)q3 * 256 + (int)threadIdx.x) * 8;
        if (e < N_EDGES) {
            int4 s0 = *(const int4*)&src[e];
            int4 s1 = *(const int4*)&src[e + 4];
            int4 d0 = *(const int4*)&dst[e];
            int4 d1 = *(const int4*)&dst[e + 4];
            int p0 = atomicAdd(&cursor[s0.x * NBLK + (d0.x >> DBLK_SHIFT)], 1);
            int p1 = atomicAdd(&cursor[s0.y * NBLK + (d0.y >> DBLK_SHIFT)], 1);
            int p2 = atomicAdd(&cursor[s0.z * NBLK + (d0.z >> DBLK_SHIFT)], 1);
            int p3 = atomicAdd(&cursor[s0.w * NBLK + (d0.w >> DBLK_SHIFT)], 1);
            int p4 = atomicAdd(&cursor[s1.x * NBLK + (d1.x >> DBLK_SHIFT)], 1);
            int p5 = atomicAdd(&cursor[s1.y * NBLK + (d1.y >> DBLK_SHIFT)], 1);
            int p6 = atomicAdd(&cursor[s1.z * NBLK + (d1.z >> DBLK_SHIFT)], 1);
            int p7 = atomicAdd(&cursor[s1.w * NBLK + (d1.w >> DBLK_SHIFT)], 1);
            csr_dst[p0] = d0.x;
            csr_dst[p1] = d0.y;
            csr_dst[p2] = d0.z;
            csr_dst[p3] = d0.w;
            csr_dst[p4] = d1.x;
            csr_dst[p5] = d1.y;
            csr_dst[p6] = d1.z;
            csr_dst[p7] = d1.w;
        }
        return;
    }

    // ---- gemm role ----
    const unsigned g = q3 * 2u + r3;        // [0, GEMM_TILES)
    const int t    = threadIdx.x;
    const int wid  = t >> 6;
    const int lane = t & 63;
    const int m0   = (int)(g >> 2) * 128;
    const int n0   = (int)(g & 3u) * 128;
    const int wm   = (wid >> 1) * 64;
    const int wn   = (wid & 1) * 64;
    const int mr   = lane & 15;
    const int q    = lane >> 4;

    f32x4 acc[4][4];
    #pragma unroll
    for (int i = 0; i < 4; ++i)
        #pragma unroll
        for (int j = 0; j < 4; ++j) acc[i][j] = 0.0f;

    const char* xb = (const char*)xh;
    const char* bb = (const char*)Bt;
    const int o1 = t * 16;         const int row1 = o1 >> 6, kb1 = o1 & 63;
    const int o2 = t * 16 + 4096;  const int row2 = o2 >> 6, kb2 = o2 & 63;
    char* lA1 = ((char*)As) + wid * 1024;
    char* lA2 = ((char*)As) + 4096 + wid * 1024;
    char* lB1 = ((char*)Bs) + wid * 1024;
    char* lB2 = ((char*)Bs) + 4096 + wid * 1024;

    for (int k0 = 0; k0 < IN_DIM; k0 += 32) {
        const int kbyte = k0 * 2;
        __builtin_amdgcn_global_load_lds(
            (const __attribute__((address_space(1))) unsigned int*)(xb + (size_t)(m0 + row1) * (IN_DIM * 2) + kbyte + kb1),
            (__attribute__((address_space(3))) unsigned int*)lA1, 16, 0, 0);
        __builtin_amdgcn_global_load_lds(
            (const __attribute__((address_space(1))) unsigned int*)(xb + (size_t)(m0 + row2) * (IN_DIM * 2) + kbyte + kb2),
            (__attribute__((address_space(3))) unsigned int*)lA2, 16, 0, 0);
        __builtin_amdgcn_global_load_lds(
            (const __attribute__((address_space(1))) unsigned int*)(bb + (size_t)(n0 + row1) * (IN_DIM * 2) + kbyte + kb1),
            (__attribute__((address_space(3))) unsigned int*)lB1, 16, 0, 0);
        __builtin_amdgcn_global_load_lds(
            (const __attribute__((address_space(1))) unsigned int*)(bb + (size_t)(n0 + row2) * (IN_DIM * 2) + kbyte + kb2),
            (__attribute__((address_space(3))) unsigned int*)lB2, 16, 0, 0);
        __syncthreads();

        bf16x8 a[4], b[4];
        #pragma unroll
        for (int i = 0; i < 4; ++i)
            a[i] = *(const bf16x8*)&As[(wm + i * 16 + mr) * 32 + q * 8];
        #pragma unroll
        for (int j = 0; j < 4; ++j)
            b[j] = *(const bf16x8*)&Bs[(wn + j * 16 + mr) * 32 + q * 8];
        #pragma unroll
        for (int i = 0; i < 4; ++i)
            #pragma unroll
            for (int j = 0; j < 4; ++j)
                acc[i][j] = __builtin_amdgcn_mfma_f32_16x16x32_bf16(a[i], b[j], acc[i][j], 0, 0, 0);
        __syncthreads();
    }

    #pragma unroll
    for (int i = 0; i < 4; ++i) {
        #pragma unroll
        for (int j = 0; j < 4; ++j) {
            int col = n0 + wn + j * 16 + mr;
            #pragma unroll
            for (int r = 0; r < 4; ++r) {
                int row = m0 + wm + i * 16 + q * 4 + r;
                if (row < N_NODES)
                    feat_h[(size_t)row * FEAT_DIM + col] = f2bf(acc[i][j][r]);
            }
        }
    }
}

// ---------------------------------------------------------------------------
// alpha projections from bf16 feat. One wave per node (all 8 heads).
// ---------------------------------------------------------------------------
__global__ __launch_bounds__(256) void alpha_kernel(const unsigned short* __restrict__ feat_h,
                                                    const float* __restrict__ att_w,
                                                    float* __restrict__ alpha_s,
                                                    float* __restrict__ alpha_d) {
    int node = (blockIdx.x * blockDim.x + threadIdx.x) >> 6;
    int lane = threadIdx.x & 63;
    if (node >= N_NODES) return;
    int h   = lane >> 3;
    int sub = lane & 7;
    bf16x8 f = *(const bf16x8*)&feat_h[(size_t)node * FEAT_DIM + lane * 8];
    float s = 0.f, d = 0.f;
    #pragma unroll
    for (int i = 0; i < 8; ++i) {
        float fv = bf2f(f[i]);
        s += fv * att_w[h * 128 + sub * 8 + i];
        d += fv * att_w[h * 128 + 64 + sub * 8 + i];
    }
    #pragma unroll
    for (int off = 1; off < 8; off <<= 1) {
        s += __shfl_xor(s, off);
        d += __shfl_xor(d, off);
    }
    if (sub == 0) {
        alpha_s[node * N_HEADS + h] = s;
        alpha_d[node * N_HEADS + h] = d;
    }
}

// ---------------------------------------------------------------------------
// Banded CSR scan (keys = src*NBLK + dst-block)
// ---------------------------------------------------------------------------
__global__ __launch_bounds__(1024) void scan_block_sums(const int* __restrict__ cnt,
                                                        int* __restrict__ partials) {
    __shared__ int wsum[16];
    const int t    = threadIdx.x;
    const int lane = t & 63;
    const int wid  = t >> 6;
    int i = blockIdx.x * 1024 + t;
    int v = (i < NKEYS) ? cnt[i] : 0;
    #pragma unroll
    for (int off = 32; off > 0; off >>= 1) v += __shfl_xor(v, off);
    if (lane == 0) wsum[wid] = v;
    __syncthreads();
    if (t < 16) {
        int u = wsum[t];
        #pragma unroll
        for (int off = 1; off < 16; off <<= 1) u += __shfl_xor(u, off);
        if (t == 0) partials[blockIdx.x] = u;
    }
}

// single-block looped exclusive scan of the KSCAN_BLK partial sums
__global__ __launch_bounds__(1024) void scan_partials(const int* __restrict__ partials,
                                                      int* __restrict__ blkoff,
                                                      int* __restrict__ keyptr) {
    __shared__ int wsum[16];
    const int t    = threadIdx.x;
    const int lane = t & 63;
    const int wid  = t >> 6;
    int carry = 0;
    for (int base = 0; base < KSCAN_BLK; base += 1024) {
        int i = base + t;
        int v = (i < KSCAN_BLK) ? partials[i] : 0;
        int incl = v;
        #pragma unroll
        for (int off = 1; off < 64; off <<= 1) {
            int u = __shfl_up(incl, off);
            if (lane >= off) incl += u;
        }
        if (lane == 63) wsum[wid] = incl;
        __syncthreads();
        if (t < 16) {
            int u = wsum[t];
            #pragma unroll
            for (int off = 1; off < 16; off <<= 1) {
                int w = __shfl_up(u, off);
                if (t >= off) u += w;
            }
            wsum[t] = u;
        }
        __syncthreads();
        int woff = (wid > 0) ? wsum[wid - 1] : 0;
        if (i < KSCAN_BLK) blkoff[i] = carry + woff + incl - v;
        carry += wsum[15];
        __syncthreads();
    }
    if (t == 0) keyptr[NKEYS] = carry;
}

// in-place capable: cursor may alias cnt
__global__ __launch_bounds__(1024) void scan_apply(const int* __restrict__ cnt,
                                                   const int* __restrict__ blkoff,
                                                   int* __restrict__ keyptr,
                                                   int* __restrict__ cursor) {
    __shared__ int wsum[16];
    const int t    = threadIdx.x;
    const int lane = t & 63;
    const int wid  = t >> 6;
    int i = blockIdx.x * 1024 + t;
    int v = (i < NKEYS) ? cnt[i] : 0;
    int incl = v;
    #pragma unroll
    for (int off = 1; off < 64; off <<= 1) {
        int u = __shfl_up(incl, off);
        if (lane >= off) incl += u;
    }
    if (lane == 63) wsum[wid] = incl;
    __syncthreads();
    if (t < 16) {
        int u = wsum[t];
        #pragma unroll
        for (int off = 1; off < 16; off <<= 1) {
            int w = __shfl_up(u, off);
            if (t >= off) u += w;
        }
        wsum[t] = u;
    }
    __syncthreads();
    int woff = (wid > 0) ? wsum[wid - 1] : 0;
    int excl = blkoff[blockIdx.x] + woff + incl - v;
    if (i < NKEYS) { keyptr[i] = excl; cursor[i] = excl; }
}

// ---------------------------------------------------------------------------
// Fused attention+aggregation, column-split into 2 sequential passes.
// 2 waves/node (edge-range split, LDS pair-reduce).
// v6: explicit 2-stage software pipeline, batch=8, named double buffers --
// batch B's 8 gathers are issued BEFORE batch A's compute consumes A, so the
// compiler cannot roll the batch into load-use-load-use (r5 had VGPR=40 ->
// only ~6 edges in flight; dataflow now forces ~16).
// ---------------------------------------------------------------------------
__global__ __launch_bounds__(256) void agg_kernel(const unsigned short* __restrict__ feat_h,
                                                  const float* __restrict__ alpha_s,
                                                  const float* __restrict__ alpha_d,
                                                  const int* __restrict__ keyptr,
                                                  const int* __restrict__ csr_dst,
                                                  float* __restrict__ out,
                                                  int hg) {
    __shared__ float red[2][64][5];
    const int wv   = __builtin_amdgcn_readfirstlane(threadIdx.x >> 6);  // uniform
    const int lane = threadIdx.x & 63;
    const int node = blockIdx.x * 2 + (wv >> 1);   // uniform (N_NODES even)
    const int half = wv & 1;                       // uniform
    const int h    = hg * 4 + (lane >> 4);

    const int start = keyptr[node * NBLK];
    const int end   = keyptr[node * NBLK + NBLK];
    const int deg   = end - start;
    const int lo    = start + ((deg * half) >> 1);
    const int hi    = start + ((deg * (half + 1)) >> 1);
    const int cnt2  = hi - lo;
    const float as  = alpha_s[node * N_HEADS + h];
    const int* cd   = csr_dst + lo;                // uniform pointer -> s_load
    const unsigned short* fb = feat_h + hg * 256 + lane * 4;

    float sacc = 0.f;
    float acc[4] = {};

    int dA[8], dB[8];
    float adA[8], adB[8];
    bf16x4 fA[8], fB[8];

    auto loadA = [&](int b) {
        const int* cb = cd + b * 8;
        #pragma unroll
        for (int k = 0; k < 8; ++k) dA[k] = cb[k];
        #pragma unroll
        for (int k = 0; k < 8; ++k) {
            adA[k] = alpha_d[(size_t)dA[k] * N_HEADS + h];
            fA[k]  = *(const bf16x4*)&fb[(size_t)dA[k] * FEAT_DIM];
        }
    };
    auto loadB = [&](int b) {
        const int* cb = cd + b * 8;
        #pragma unroll
        for (int k = 0; k < 8; ++k) dB[k] = cb[k];
        #pragma unroll
        for (int k = 0; k < 8; ++k) {
            adB[k] = alpha_d[(size_t)dB[k] * N_HEADS + h];
            fB[k]  = *(const bf16x4*)&fb[(size_t)dB[k] * FEAT_DIM];
        }
    };
    auto computeA = [&]() {
        #pragma unroll
        for (int k = 0; k < 8; ++k) {
            float z = as + adA[k]; z = z > 0.f ? z : LRELU_A * z;
            float e = __expf(z);
            sacc += e;
            acc[0] += e * bf2f(fA[k][0]);
            acc[1] += e * bf2f(fA[k][1]);
            acc[2] += e * bf2f(fA[k][2]);
            acc[3] += e * bf2f(fA[k][3]);
        }
    };
    auto computeB = [&]() {
        #pragma unroll
        for (int k = 0; k < 8; ++k) {
            float z = as + adB[k]; z = z > 0.f ? z : LRELU_A * z;
            float e = __expf(z);
            sacc += e;
            acc[0] += e * bf2f(fB[k][0]);
            acc[1] += e * bf2f(fB[k][1]);
            acc[2] += e * bf2f(fB[k][2]);
            acc[3] += e * bf2f(fB[k][3]);
        }
    };

    const int nb = cnt2 >> 3;   // number of full 8-edge batches
    if (nb > 0) {
        loadA(0);
        int b = 0;
        for (; b + 2 <= nb; b += 2) {
            loadB(b + 1);               // issue next batch's gathers
            computeA();                 // consume current (hides B latency)
            if (b + 2 < nb) loadA(b + 2);
            computeB();
        }
        if (b < nb) computeA();         // odd tail batch (already loaded)
    }
    for (int j = nb * 8; j < cnt2; ++j) {
        int dd = cd[j];
        float ad0 = alpha_d[(size_t)dd * N_HEADS + h];
        bf16x4 f0 = *(const bf16x4*)&fb[(size_t)dd * FEAT_DIM];
        float z = as + ad0; z = z > 0.f ? z : LRELU_A * z;
        float e0 = __expf(z);
        sacc += e0;
        #pragma unroll
        for (int i = 0; i < 4; ++i) acc[i] += e0 * bf2f(f0[i]);
    }

    const int pr = wv >> 1;
    if (half == 1) {
        #pragma unroll
        for (int i = 0; i < 4; ++i) red[pr][lane][i] = acc[i];
        red[pr][lane][4] = sacc;
    }
    __syncthreads();
    if (half == 0) {
        #pragma unroll
        for (int i = 0; i < 4; ++i) acc[i] += red[pr][lane][i];
        sacc += red[pr][lane][4];
        const float inv = (deg > 0) ? 1.f / sacc : 0.f;
        f32x4 o0 = { fmaxf(acc[0] * inv, 0.f), fmaxf(acc[1] * inv, 0.f),
                     fmaxf(acc[2] * inv, 0.f), fmaxf(acc[3] * inv, 0.f) };
        f32x4* op = (f32x4*)(out + (size_t)node * FEAT_DIM + hg * 256 + lane * 4);
        __builtin_nontemporal_store(o0, op);
    }
}

// ---------------------------------------------------------------------------
extern "C" void kernel_launch(void* const* d_in, const int* in_sizes, int n_in,
                              void* d_out, int out_size, void* d_ws, size_t ws_size,
                              hipStream_t stream) {
    const float* x     = (const float*)d_in[0];
    const float* W     = (const float*)d_in[1];
    const float* att_w = (const float*)d_in[2];
    const int*   src   = (const int*)d_in[3];
    const int*   dst   = (const int*)d_in[4];
    float* out = (float*)d_out;

    char* ws = (char*)d_ws;
    size_t off = 0;
    auto alloc = [&](size_t bytes) {
        void* p = ws + off;
        off += (bytes + 255) & ~(size_t)255;
        return p;
    };
    unsigned short* feat_h = (unsigned short*)alloc((size_t)N_NODES * FEAT_DIM * sizeof(short)); // 51.2 MB
    unsigned short* xh     = (unsigned short*)alloc((size_t)M_PAD * IN_DIM * sizeof(short));     // 51.2 MB
    unsigned short* Bt     = (unsigned short*)alloc((size_t)FEAT_DIM * IN_DIM * sizeof(short));  // 0.5 MB
    float* alpha_s = (float*)alloc((size_t)N_NODES * N_HEADS * sizeof(float));                   // 1.6 MB
    float* alpha_d = (float*)alloc((size_t)N_NODES * N_HEADS * sizeof(float));                   // 1.6 MB
    int*   cnt     = (int*)alloc((size_t)NKEYS * sizeof(int));                                   // 5.0 MB
    int*   keyptr  = (int*)alloc((size_t)(NKEYS + 1) * sizeof(int));                             // 5.0 MB
    int*   csr_dst = (int*)alloc((size_t)N_EDGES * sizeof(int));                                 // 6.4 MB
    int*   partials = (int*)alloc((size_t)KSCAN_BLK * sizeof(int));
    int*   blkoff   = (int*)alloc((size_t)KSCAN_BLK * sizeof(int));
    int*   cursor   = cnt;   // in-place: scan_apply reads cnt[i] then writes cursor[i]

    (void)hipMemsetAsync(cnt, 0, (size_t)NKEYS * sizeof(int), stream);

    // Launch 1: convert (BW-bound) || count (atomic-bound)
    convert_count<<<CVT_BLK + EDGE_BLK, 256, 0, stream>>>(x, xh, src, dst, cnt);
    prep_b<<<(FEAT_DIM * IN_DIM + 255) / 256, 256, 0, stream>>>(W, Bt);

    // scan chain (needs cnt)
    scan_block_sums<<<KSCAN_BLK, 1024, 0, stream>>>(cnt, partials);
    scan_partials<<<1, 1024, 0, stream>>>(partials, blkoff, keyptr);
    scan_apply<<<KSCAN_BLK, 1024, 0, stream>>>(cnt, blkoff, keyptr, cursor);

    // Launch 2: gemm (MFMA-bound, needs xh) || scatter (atomic-bound, needs keyptr)
    gemm_scatter<<<3 * EDGE_BLK, 256, 0, stream>>>(xh, Bt, feat_h, src, dst, cursor, csr_dst);

    alpha_kernel<<<(N_NODES + 3) / 4, 256, 0, stream>>>(feat_h, att_w, alpha_s, alpha_d);

    agg_kernel<<<N_NODES / 2, 256, 0, stream>>>(feat_h, alpha_s, alpha_d, keyptr, csr_dst, out, 0);
    agg_kernel<<<N_NODES / 2, 256, 0, stream>>>(feat_h, alpha_s, alpha_d, keyptr, csr_dst, out, 1);
}

// Round 7
// 596.321 us; speedup vs baseline: 1.0132x; 1.0132x over previous
//
#include <hip/hip_runtime.h>
#include <math.h>

#define N_NODES   50000
#define N_EDGES   1600000
#define N_HEADS   8
#define IN_DIM    512
#define OUT_DIM   64
#define FEAT_DIM  512            // N_HEADS * OUT_DIM
#define LRELU_A   0.2f
#define M_TILES   391            // ceil(50000/128)
#define M_PAD     (M_TILES*128)  // 50048 rows in xh (tail rows read but never stored)

// dst-banding keys with per-node DIAGONAL ROTATION: edge (s,d) stored under
// band ((d>>11) - p0(s)) mod 25, p0(s)=s>>11. Read flat per node, the edge
// list sweeps dst space starting at band p0(s) and wrapping. Launch order ~
// node order => co-resident blocks share their current band => the active
// feat band stays L2-resident. Zero inner-loop cost (rotation is in layout).
#define DBLK_SHIFT 11
#define NBLK       25                       // ceil(50000/2048)
#define NKEYS      (N_NODES * NBLK)         // 1,250,000
#define KSCAN_BLK  ((NKEYS + 1023) / 1024)  // 1221

// fused-launch geometry
#define EDGE_BLK   782                      // ceil(1.6M / (256*8))
#define CVT_BLK    25000                    // 25.6M bf16 / 4-per-thread / 256
#define GEMM_TILES 1564                     // 391 * 4

typedef __attribute__((ext_vector_type(8))) short bf16x8;
typedef __attribute__((ext_vector_type(4))) short bf16x4;
typedef __attribute__((ext_vector_type(4))) float f32x4;

__device__ inline unsigned short f2bf(float f) {
    unsigned int u = __float_as_uint(f);
    u = (u + 0x7FFFu + ((u >> 16) & 1u)) >> 16;   // round-to-nearest-even
    return (unsigned short)u;
}
__device__ inline float bf2f(short s) {
    return __uint_as_float(((unsigned int)(unsigned short)s) << 16);
}

// rotated band key: s*25 + ((d>>11) - (s>>11) mod 25). s>>11 is in [0,24].
__device__ inline int bkey(int s, int d) {
    int r = (d >> DBLK_SHIFT) - (s >> DBLK_SHIFT);
    r += (r < 0) ? NBLK : 0;
    return s * NBLK + r;
}

// ---------------------------------------------------------------------------
// Fused: x (fp32 [N][512]) -> xh (bf16)   ||   rotated-banded-key histogram.
// ---------------------------------------------------------------------------
__global__ __launch_bounds__(256) void convert_count(const float* __restrict__ x,
                                                     unsigned short* __restrict__ xh,
                                                     const int* __restrict__ src,
                                                     const int* __restrict__ dst,
                                                     int* __restrict__ cnt) {
    const int id = blockIdx.x;
    if (id < 2 * EDGE_BLK && (id & 1)) {
        // ---- count role (unroll 8) ----
        const int blk = id >> 1;
        const int e = (blk * 256 + threadIdx.x) * 8;
        if (e < N_EDGES) {
            int4 s0 = *(const int4*)&src[e];
            int4 s1 = *(const int4*)&src[e + 4];
            int4 d0 = *(const int4*)&dst[e];
            int4 d1 = *(const int4*)&dst[e + 4];
            atomicAdd(&cnt[bkey(s0.x, d0.x)], 1);
            atomicAdd(&cnt[bkey(s0.y, d0.y)], 1);
            atomicAdd(&cnt[bkey(s0.z, d0.z)], 1);
            atomicAdd(&cnt[bkey(s0.w, d0.w)], 1);
            atomicAdd(&cnt[bkey(s1.x, d1.x)], 1);
            atomicAdd(&cnt[bkey(s1.y, d1.y)], 1);
            atomicAdd(&cnt[bkey(s1.z, d1.z)], 1);
            atomicAdd(&cnt[bkey(s1.w, d1.w)], 1);
        }
        return;
    }
    // ---- convert role ----
    const int c = (id < 2 * EDGE_BLK) ? (id >> 1) : (id - EDGE_BLK);
    const int i = c * 256 + threadIdx.x;   // float4 index
    if (i >= N_NODES * IN_DIM / 4) return;
    float4 v = ((const float4*)x)[i];
    ushort4 o;
    o.x = f2bf(v.x); o.y = f2bf(v.y); o.z = f2bf(v.z); o.w = f2bf(v.w);
    ((ushort4*)xh)[i] = o;
}

// ---------------------------------------------------------------------------
// W (fp32 [8][512][64]) -> Bt (bf16 [n=512][k=512]), Bt[n][k] = W[n>>6][k][n&63]
// ---------------------------------------------------------------------------
__global__ __launch_bounds__(256) void prep_b(const float* __restrict__ W,
                                              unsigned short* __restrict__ Bt) {
    int t = blockIdx.x * blockDim.x + threadIdx.x;   // t = n*512 + k
    if (t >= FEAT_DIM * IN_DIM) return;
    int n = t >> 9, k = t & 511;
    int h = n >> 6, o = n & 63;
    Bt[t] = f2bf(W[(size_t)h * IN_DIM * OUT_DIM + (size_t)k * OUT_DIM + o]);
}

// ---------------------------------------------------------------------------
// Fused: MFMA GEMM (feat = xh @ Bt^T)  ||  rotated-banded scatter (CSR fill).
// ---------------------------------------------------------------------------
__global__ __launch_bounds__(256) void gemm_scatter(const unsigned short* __restrict__ xh,
                                                    const unsigned short* __restrict__ Bt,
                                                    unsigned short* __restrict__ feat_h,
                                                    const int* __restrict__ src,
                                                    const int* __restrict__ dst,
                                                    int* __restrict__ cursor,
                                                    int* __restrict__ csr_dst) {
    __shared__ __align__(16) unsigned short As[128 * 32];  // [m][k], 64 B rows
    __shared__ __align__(16) unsigned short Bs[128 * 32];  // [n][k]
    const unsigned id = blockIdx.x;
    const unsigned q3 = id / 3u;
    const unsigned r3 = id - q3 * 3u;

    if (r3 == 2u) {
        // ---- scatter role (unroll 8) ----
        const int e = ((int)q3 * 256 + (int)threadIdx.x) * 8;
        if (e < N_EDGES) {
            int4 s0 = *(const int4*)&src[e];
            int4 s1 = *(const int4*)&src[e + 4];
            int4 d0 = *(const int4*)&dst[e];
            int4 d1 = *(const int4*)&dst[e + 4];
            int p0 = atomicAdd(&cursor[bkey(s0.x, d0.x)], 1);
            int p1 = atomicAdd(&cursor[bkey(s0.y, d0.y)], 1);
            int p2 = atomicAdd(&cursor[bkey(s0.z, d0.z)], 1);
            int p3 = atomicAdd(&cursor[bkey(s0.w, d0.w)], 1);
            int p4 = atomicAdd(&cursor[bkey(s1.x, d1.x)], 1);
            int p5 = atomicAdd(&cursor[bkey(s1.y, d1.y)], 1);
            int p6 = atomicAdd(&cursor[bkey(s1.z, d1.z)], 1);
            int p7 = atomicAdd(&cursor[bkey(s1.w, d1.w)], 1);
            csr_dst[p0] = d0.x;
            csr_dst[p1] = d0.y;
            csr_dst[p2] = d0.z;
            csr_dst[p3] = d0.w;
            csr_dst[p4] = d1.x;
            csr_dst[p5] = d1.y;
            csr_dst[p6] = d1.z;
            csr_dst[p7] = d1.w;
        }
        return;
    }

    // ---- gemm role ----
    const unsigned g = q3 * 2u + r3;        // [0, GEMM_TILES)
    const int t    = threadIdx.x;
    const int wid  = t >> 6;
    const int lane = t & 63;
    const int m0   = (int)(g >> 2) * 128;
    const int n0   = (int)(g & 3u) * 128;
    const int wm   = (wid >> 1) * 64;
    const int wn   = (wid & 1) * 64;
    const int mr   = lane & 15;
    const int q    = lane >> 4;

    f32x4 acc[4][4];
    #pragma unroll
    for (int i = 0; i < 4; ++i)
        #pragma unroll
        for (int j = 0; j < 4; ++j) acc[i][j] = 0.0f;

    const char* xb = (const char*)xh;
    const char* bb = (const char*)Bt;
    const int o1 = t * 16;         const int row1 = o1 >> 6, kb1 = o1 & 63;
    const int o2 = t * 16 + 4096;  const int row2 = o2 >> 6, kb2 = o2 & 63;
    char* lA1 = ((char*)As) + wid * 1024;
    char* lA2 = ((char*)As) + 4096 + wid * 1024;
    char* lB1 = ((char*)Bs) + wid * 1024;
    char* lB2 = ((char*)Bs) + 4096 + wid * 1024;

    for (int k0 = 0; k0 < IN_DIM; k0 += 32) {
        const int kbyte = k0 * 2;
        __builtin_amdgcn_global_load_lds(
            (const __attribute__((address_space(1))) unsigned int*)(xb + (size_t)(m0 + row1) * (IN_DIM * 2) + kbyte + kb1),
            (__attribute__((address_space(3))) unsigned int*)lA1, 16, 0, 0);
        __builtin_amdgcn_global_load_lds(
            (const __attribute__((address_space(1))) unsigned int*)(xb + (size_t)(m0 + row2) * (IN_DIM * 2) + kbyte + kb2),
            (__attribute__((address_space(3))) unsigned int*)lA2, 16, 0, 0);
        __builtin_amdgcn_global_load_lds(
            (const __attribute__((address_space(1))) unsigned int*)(bb + (size_t)(n0 + row1) * (IN_DIM * 2) + kbyte + kb1),
            (__attribute__((address_space(3))) unsigned int*)lB1, 16, 0, 0);
        __builtin_amdgcn_global_load_lds(
            (const __attribute__((address_space(1))) unsigned int*)(bb + (size_t)(n0 + row2) * (IN_DIM * 2) + kbyte + kb2),
            (__attribute__((address_space(3))) unsigned int*)lB2, 16, 0, 0);
        __syncthreads();

        bf16x8 a[4], b[4];
        #pragma unroll
        for (int i = 0; i < 4; ++i)
            a[i] = *(const bf16x8*)&As[(wm + i * 16 + mr) * 32 + q * 8];
        #pragma unroll
        for (int j = 0; j < 4; ++j)
            b[j] = *(const bf16x8*)&Bs[(wn + j * 16 + mr) * 32 + q * 8];
        #pragma unroll
        for (int i = 0; i < 4; ++i)
            #pragma unroll
            for (int j = 0; j < 4; ++j)
                acc[i][j] = __builtin_amdgcn_mfma_f32_16x16x32_bf16(a[i], b[j], acc[i][j], 0, 0, 0);
        __syncthreads();
    }

    #pragma unroll
    for (int i = 0; i < 4; ++i) {
        #pragma unroll
        for (int j = 0; j < 4; ++j) {
            int col = n0 + wn + j * 16 + mr;
            #pragma unroll
            for (int r = 0; r < 4; ++r) {
                int row = m0 + wm + i * 16 + q * 4 + r;
                if (row < N_NODES)
                    feat_h[(size_t)row * FEAT_DIM + col] = f2bf(acc[i][j][r]);
            }
        }
    }
}

// ---------------------------------------------------------------------------
// alpha projections from bf16 feat. One wave per node (all 8 heads).
// ---------------------------------------------------------------------------
__global__ __launch_bounds__(256) void alpha_kernel(const unsigned short* __restrict__ feat_h,
                                                    const float* __restrict__ att_w,
                                                    float* __restrict__ alpha_s,
                                                    float* __restrict__ alpha_d) {
    int node = (blockIdx.x * blockDim.x + threadIdx.x) >> 6;
    int lane = threadIdx.x & 63;
    if (node >= N_NODES) return;
    int h   = lane >> 3;
    int sub = lane & 7;
    bf16x8 f = *(const bf16x8*)&feat_h[(size_t)node * FEAT_DIM + lane * 8];
    float s = 0.f, d = 0.f;
    #pragma unroll
    for (int i = 0; i < 8; ++i) {
        float fv = bf2f(f[i]);
        s += fv * att_w[h * 128 + sub * 8 + i];
        d += fv * att_w[h * 128 + 64 + sub * 8 + i];
    }
    #pragma unroll
    for (int off = 1; off < 8; off <<= 1) {
        s += __shfl_xor(s, off);
        d += __shfl_xor(d, off);
    }
    if (sub == 0) {
        alpha_s[node * N_HEADS + h] = s;
        alpha_d[node * N_HEADS + h] = d;
    }
}

// ---------------------------------------------------------------------------
// Banded CSR scan (keys = rotated (src, dst-block))
// ---------------------------------------------------------------------------
__global__ __launch_bounds__(1024) void scan_block_sums(const int* __restrict__ cnt,
                                                        int* __restrict__ partials) {
    __shared__ int wsum[16];
    const int t    = threadIdx.x;
    const int lane = t & 63;
    const int wid  = t >> 6;
    int i = blockIdx.x * 1024 + t;
    int v = (i < NKEYS) ? cnt[i] : 0;
    #pragma unroll
    for (int off = 32; off > 0; off >>= 1) v += __shfl_xor(v, off);
    if (lane == 0) wsum[wid] = v;
    __syncthreads();
    if (t < 16) {
        int u = wsum[t];
        #pragma unroll
        for (int off = 1; off < 16; off <<= 1) u += __shfl_xor(u, off);
        if (t == 0) partials[blockIdx.x] = u;
    }
}

// single-block looped exclusive scan of the KSCAN_BLK partial sums
__global__ __launch_bounds__(1024) void scan_partials(const int* __restrict__ partials,
                                                      int* __restrict__ blkoff,
                                                      int* __restrict__ keyptr) {
    __shared__ int wsum[16];
    const int t    = threadIdx.x;
    const int lane = t & 63;
    const int wid  = t >> 6;
    int carry = 0;
    for (int base = 0; base < KSCAN_BLK; base += 1024) {
        int i = base + t;
        int v = (i < KSCAN_BLK) ? partials[i] : 0;
        int incl = v;
        #pragma unroll
        for (int off = 1; off < 64; off <<= 1) {
            int u = __shfl_up(incl, off);
            if (lane >= off) incl += u;
        }
        if (lane == 63) wsum[wid] = incl;
        __syncthreads();
        if (t < 16) {
            int u = wsum[t];
            #pragma unroll
            for (int off = 1; off < 16; off <<= 1) {
                int w = __shfl_up(u, off);
                if (t >= off) u += w;
            }
            wsum[t] = u;
        }
        __syncthreads();
        int woff = (wid > 0) ? wsum[wid - 1] : 0;
        if (i < KSCAN_BLK) blkoff[i] = carry + woff + incl - v;
        carry += wsum[15];
        __syncthreads();
    }
    if (t == 0) keyptr[NKEYS] = carry;
}

// in-place capable: cursor may alias cnt
__global__ __launch_bounds__(1024) void scan_apply(const int* __restrict__ cnt,
                                                   const int* __restrict__ blkoff,
                                                   int* __restrict__ keyptr,
                                                   int* __restrict__ cursor) {
    __shared__ int wsum[16];
    const int t    = threadIdx.x;
    const int lane = t & 63;
    const int wid  = t >> 6;
    int i = blockIdx.x * 1024 + t;
    int v = (i < NKEYS) ? cnt[i] : 0;
    int incl = v;
    #pragma unroll
    for (int off = 1; off < 64; off <<= 1) {
        int u = __shfl_up(incl, off);
        if (lane >= off) incl += u;
    }
    if (lane == 63) wsum[wid] = incl;
    __syncthreads();
    if (t < 16) {
        int u = wsum[t];
        #pragma unroll
        for (int off = 1; off < 16; off <<= 1) {
            int w = __shfl_up(u, off);
            if (t >= off) u += w;
        }
        wsum[t] = u;
    }
    __syncthreads();
    int woff = (wid > 0) ? wsum[wid - 1] : 0;
    int excl = blkoff[blockIdx.x] + woff + incl - v;
    if (i < NKEYS) { keyptr[i] = excl; cursor[i] = excl; }
}

// ---------------------------------------------------------------------------
// Fused attention+aggregation, column-split into 2 sequential passes
// (hg=0: heads 0-3, hg=1: heads 4-7; 512 B/edge gather from a 25.6 MB
// half-table). Adjacency is rotated-band-sorted: read flat it sweeps dst
// space starting at band p0(node)=node>>11 and wrapping, so co-resident
// blocks (launch order ~ node order) share the same moving L2 band.
// 2 waves/node (edge-range split, LDS pair-reduce), flat unroll-16 stream.
// ---------------------------------------------------------------------------
__global__ __launch_bounds__(256) void agg_kernel(const unsigned short* __restrict__ feat_h,
                                                  const float* __restrict__ alpha_s,
                                                  const float* __restrict__ alpha_d,
                                                  const int* __restrict__ keyptr,
                                                  const int* __restrict__ csr_dst,
                                                  float* __restrict__ out,
                                                  int hg) {
    __shared__ float red[2][64][5];
    const int wv   = __builtin_amdgcn_readfirstlane(threadIdx.x >> 6);  // uniform
    const int lane = threadIdx.x & 63;
    const int node = blockIdx.x * 2 + (wv >> 1);   // uniform (N_NODES even)
    const int half = wv & 1;                       // uniform
    const int h    = hg * 4 + (lane >> 4);

    const int start = keyptr[node * NBLK];
    const int end   = keyptr[node * NBLK + NBLK];
    const int deg   = end - start;
    const int lo    = start + ((deg * half) >> 1);
    const int hi    = start + ((deg * (half + 1)) >> 1);
    const int cnt2  = hi - lo;
    const float as  = alpha_s[node * N_HEADS + h];
    const int* cd   = csr_dst + lo;                // uniform pointer -> s_load
    const unsigned short* fb = feat_h + hg * 256 + lane * 4;

    float sacc = 0.f;
    float acc[4] = {};

    int j = 0;
    for (; j + 16 <= cnt2; j += 16) {
        int d[16];
        #pragma unroll
        for (int k = 0; k < 16; ++k) d[k] = cd[j + k];
        float ad[16];
        #pragma unroll
        for (int k = 0; k < 16; ++k) ad[k] = alpha_d[(size_t)d[k] * N_HEADS + h];
        bf16x4 f[16];
        #pragma unroll
        for (int k = 0; k < 16; ++k)
            f[k] = *(const bf16x4*)&fb[(size_t)d[k] * FEAT_DIM];
        float e[16];
        #pragma unroll
        for (int k = 0; k < 16; ++k) {
            float z = as + ad[k];
            z = z > 0.f ? z : LRELU_A * z;
            e[k] = __expf(z);
        }
        float s0 = 0.f;
        #pragma unroll
        for (int k = 0; k < 16; ++k) s0 += e[k];
        sacc += s0;
        #pragma unroll
        for (int i = 0; i < 4; ++i) {
            float a = acc[i];
            #pragma unroll
            for (int k = 0; k < 16; ++k) a += e[k] * bf2f(f[k][i]);
            acc[i] = a;
        }
    }
    for (; j + 4 <= cnt2; j += 4) {
        int d[4];
        #pragma unroll
        for (int k = 0; k < 4; ++k) d[k] = cd[j + k];
        float ad[4];
        #pragma unroll
        for (int k = 0; k < 4; ++k) ad[k] = alpha_d[(size_t)d[k] * N_HEADS + h];
        bf16x4 f[4];
        #pragma unroll
        for (int k = 0; k < 4; ++k)
            f[k] = *(const bf16x4*)&fb[(size_t)d[k] * FEAT_DIM];
        float e[4];
        #pragma unroll
        for (int k = 0; k < 4; ++k) {
            float z = as + ad[k];
            z = z > 0.f ? z : LRELU_A * z;
            e[k] = __expf(z);
        }
        sacc += (e[0] + e[1]) + (e[2] + e[3]);
        #pragma unroll
        for (int i = 0; i < 4; ++i) {
            float a = acc[i];
            #pragma unroll
            for (int k = 0; k < 4; ++k) a += e[k] * bf2f(f[k][i]);
            acc[i] = a;
        }
    }
    for (; j < cnt2; ++j) {
        int dd = cd[j];
        float ad0 = alpha_d[(size_t)dd * N_HEADS + h];
        bf16x4 f0 = *(const bf16x4*)&fb[(size_t)dd * FEAT_DIM];
        float z = as + ad0; z = z > 0.f ? z : LRELU_A * z;
        float e0 = __expf(z);
        sacc += e0;
        #pragma unroll
        for (int i = 0; i < 4; ++i) acc[i] += e0 * bf2f(f0[i]);
    }

    const int pr = wv >> 1;
    if (half == 1) {
        #pragma unroll
        for (int i = 0; i < 4; ++i) red[pr][lane][i] = acc[i];
        red[pr][lane][4] = sacc;
    }
    __syncthreads();
    if (half == 0) {
        #pragma unroll
        for (int i = 0; i < 4; ++i) acc[i] += red[pr][lane][i];
        sacc += red[pr][lane][4];
        const float inv = (deg > 0) ? 1.f / sacc : 0.f;
        f32x4 o0 = { fmaxf(acc[0] * inv, 0.f), fmaxf(acc[1] * inv, 0.f),
                     fmaxf(acc[2] * inv, 0.f), fmaxf(acc[3] * inv, 0.f) };
        f32x4* op = (f32x4*)(out + (size_t)node * FEAT_DIM + hg * 256 + lane * 4);
        __builtin_nontemporal_store(o0, op);
    }
}

// ---------------------------------------------------------------------------
extern "C" void kernel_launch(void* const* d_in, const int* in_sizes, int n_in,
                              void* d_out, int out_size, void* d_ws, size_t ws_size,
                              hipStream_t stream) {
    const float* x     = (const float*)d_in[0];
    const float* W     = (const float*)d_in[1];
    const float* att_w = (const float*)d_in[2];
    const int*   src   = (const int*)d_in[3];
    const int*   dst   = (const int*)d_in[4];
    float* out = (float*)d_out;

    char* ws = (char*)d_ws;
    size_t off = 0;
    auto alloc = [&](size_t bytes) {
        void* p = ws + off;
        off += (bytes + 255) & ~(size_t)255;
        return p;
    };
    unsigned short* feat_h = (unsigned short*)alloc((size_t)N_NODES * FEAT_DIM * sizeof(short)); // 51.2 MB
    unsigned short* xh     = (unsigned short*)alloc((size_t)M_PAD * IN_DIM * sizeof(short));     // 51.2 MB
    unsigned short* Bt     = (unsigned short*)alloc((size_t)FEAT_DIM * IN_DIM * sizeof(short));  // 0.5 MB
    float* alpha_s = (float*)alloc((size_t)N_NODES * N_HEADS * sizeof(float));                   // 1.6 MB
    float* alpha_d = (float*)alloc((size_t)N_NODES * N_HEADS * sizeof(float));                   // 1.6 MB
    int*   cnt     = (int*)alloc((size_t)NKEYS * sizeof(int));                                   // 5.0 MB
    int*   keyptr  = (int*)alloc((size_t)(NKEYS + 1) * sizeof(int));                             // 5.0 MB
    int*   csr_dst = (int*)alloc((size_t)N_EDGES * sizeof(int));                                 // 6.4 MB
    int*   partials = (int*)alloc((size_t)KSCAN_BLK * sizeof(int));
    int*   blkoff   = (int*)alloc((size_t)KSCAN_BLK * sizeof(int));
    int*   cursor   = cnt;   // in-place: scan_apply reads cnt[i] then writes cursor[i]

    (void)hipMemsetAsync(cnt, 0, (size_t)NKEYS * sizeof(int), stream);

    // Launch 1: convert (BW-bound) || count (atomic-bound)
    convert_count<<<CVT_BLK + EDGE_BLK, 256, 0, stream>>>(x, xh, src, dst, cnt);
    prep_b<<<(FEAT_DIM * IN_DIM + 255) / 256, 256, 0, stream>>>(W, Bt);

    // scan chain (needs cnt)
    scan_block_sums<<<KSCAN_BLK, 1024, 0, stream>>>(cnt, partials);
    scan_partials<<<1, 1024, 0, stream>>>(partials, blkoff, keyptr);
    scan_apply<<<KSCAN_BLK, 1024, 0, stream>>>(cnt, blkoff, keyptr, cursor);

    // Launch 2: gemm (MFMA-bound, needs xh) || scatter (atomic-bound, needs keyptr)
    gemm_scatter<<<3 * EDGE_BLK, 256, 0, stream>>>(xh, Bt, feat_h, src, dst, cursor, csr_dst);

    alpha_kernel<<<(N_NODES + 3) / 4, 256, 0, stream>>>(feat_h, att_w, alpha_s, alpha_d);

    agg_kernel<<<N_NODES / 2, 256, 0, stream>>>(feat_h, alpha_s, alpha_d, keyptr, csr_dst, out, 0);
    agg_kernel<<<N_NODES / 2, 256, 0, stream>>>(feat_h, alpha_s, alpha_d, keyptr, csr_dst, out, 1);
}